// Round 1
// baseline (400.300 us; speedup 1.0000x reference)
//
#include <hip/hip_runtime.h>

#define D 128

// ---------------- wave helpers ----------------
__device__ __forceinline__ float wred_max(float v){
#pragma unroll
  for (int o = 1; o < 64; o <<= 1) v = fmaxf(v, __shfl_xor(v, o, 64));
  return v;
}
__device__ __forceinline__ float wred_sum(float v){
#pragma unroll
  for (int o = 1; o < 64; o <<= 1) v += __shfl_xor(v, o, 64);
  return v;
}

// ---------------- CSR build ----------------
__global__ __launch_bounds__(256) void k_hist(const int* __restrict__ dst, int E, int EP,
                                              int* __restrict__ counts){
  int e = blockIdx.x * blockDim.x + threadIdx.x;
  if (e >= EP) return;
  int d = (e < E) ? dst[e] : (e - E);   // tail = self loops
  atomicAdd(&counts[d], 1);
}

__global__ __launch_bounds__(1024) void k_scan(const int* __restrict__ counts,
                                               int* __restrict__ rowptr, int n){
  __shared__ int wsum[16];
  __shared__ int sh_carry;
  int tid = threadIdx.x, lane = tid & 63, wid = tid >> 6;
  if (tid == 0) sh_carry = 0;
  __syncthreads();
  for (int base = 0; base < n; base += 1024){
    int carry = sh_carry;
    int i = base + tid;
    int v = (i < n) ? counts[i] : 0;
    int x = v;
#pragma unroll
    for (int o = 1; o < 64; o <<= 1){ int t = __shfl_up(x, o, 64); if (lane >= o) x += t; }
    if (lane == 63) wsum[wid] = x;
    __syncthreads();
    if (tid == 0){
      int s = 0;
      for (int w = 0; w < 16; w++){ int t = wsum[w]; wsum[w] = s; s += t; }
      sh_carry = carry + s;
    }
    __syncthreads();
    if (i < n) rowptr[i] = carry + wsum[wid] + x - v;   // exclusive
  }
  if (threadIdx.x == 0) rowptr[n] = sh_carry;
}

__global__ __launch_bounds__(256) void k_fill(const int* __restrict__ src, const int* __restrict__ dst,
                                              int E, int EP, const int* __restrict__ rowptr,
                                              int* __restrict__ cursor, int* __restrict__ csr){
  int e = blockIdx.x * blockDim.x + threadIdx.x;
  if (e >= EP) return;
  int s, d;
  if (e < E){ s = src[e]; d = dst[e]; } else { s = d = e - E; }
  int pos = rowptr[d] + atomicAdd(&cursor[d], 1);
  csr[pos] = s;
}

// ---------------- GEMM: C[n x 128] = A[n x 128] @ W[128 x 128] ----------------
// In-place safe (C may alias A): each block reads only its own rows, fully,
// across all k-steps before the epilogue stores.
__global__ __launch_bounds__(256) void k_gemm(const float* A, const float* __restrict__ W,
                                              float* C, int nrows){
  __shared__ float sA[64][32];    // 8 KB
  __shared__ float sW[32][128];   // 16 KB
  int tid = threadIdx.x;
  int r0 = blockIdx.x * 64;
  int tx = tid & 31;        // cols tx*4 .. tx*4+3
  int ty = tid >> 5;        // rows ty*8 .. ty*8+7
  float4 acc[8];
#pragma unroll
  for (int i = 0; i < 8; i++) acc[i] = make_float4(0.f, 0.f, 0.f, 0.f);

  for (int kt = 0; kt < 128; kt += 32){
    // stage A tile (64 x 32): 512 float4 slots, 2 per thread
#pragma unroll
    for (int i = 0; i < 2; i++){
      int slot = tid + i * 256;
      int r = slot >> 3, kq = slot & 7;
      int gr = r0 + r; if (gr > nrows - 1) gr = nrows - 1;
      float4 v = *(const float4*)&A[(size_t)gr * D + kt + kq * 4];
      *(float4*)&sA[r][kq * 4] = v;
    }
    // stage W tile (32 x 128): 1024 float4 slots, 4 per thread
#pragma unroll
    for (int i = 0; i < 4; i++){
      int slot = tid + i * 256;
      int k = slot >> 5, cq = slot & 31;
      *(float4*)&sW[k][cq * 4] = *(const float4*)&W[(size_t)(kt + k) * D + cq * 4];
    }
    __syncthreads();
#pragma unroll
    for (int k = 0; k < 32; k++){
      float4 w = *(const float4*)&sW[k][tx * 4];
#pragma unroll
      for (int i = 0; i < 8; i++){
        float a = sA[ty * 8 + i][k];
        acc[i].x += a * w.x; acc[i].y += a * w.y; acc[i].z += a * w.z; acc[i].w += a * w.w;
      }
    }
    __syncthreads();
  }
#pragma unroll
  for (int i = 0; i < 8; i++){
    int gr = r0 + ty * 8 + i;
    if (gr < nrows) *(float4*)&C[(size_t)gr * D + tx * 4] = acc[i];
  }
}

// ---------------- attention dots: as[n]=h[n]·a_src, ad[n]=h[n]·a_dst ----------------
__global__ __launch_bounds__(256) void k_dots(const float* __restrict__ h,
                                              const float* __restrict__ a_src,
                                              const float* __restrict__ a_dst,
                                              float* __restrict__ as_, float* __restrict__ ad_,
                                              int n){
  int w = (blockIdx.x * 256 + threadIdx.x) >> 6;
  if (w >= n) return;
  int lane = threadIdx.x & 63;
  float2 hv = *(const float2*)&h[(size_t)w * D + lane * 2];
  float2 s2 = *(const float2*)&a_src[lane * 2];
  float2 d2 = *(const float2*)&a_dst[lane * 2];
  float ps = hv.x * s2.x + hv.y * s2.y;
  float pd = hv.x * d2.x + hv.y * d2.y;
#pragma unroll
  for (int o = 1; o < 64; o <<= 1){ ps += __shfl_xor(ps, o, 64); pd += __shfl_xor(pd, o, 64); }
  if (lane == 0){ as_[w] = ps; ad_[w] = pd; }
}

// ---------------- aggregation: one wave per destination node ----------------
__global__ __launch_bounds__(256) void k_agg(const float* __restrict__ h,
                                             const int* __restrict__ csr,
                                             const int* __restrict__ rowptr,
                                             const float* __restrict__ asrc,
                                             const float* __restrict__ adst,
                                             const float* __restrict__ bias,
                                             float* __restrict__ out, int relu, int n){
  int node = (blockIdx.x * 256 + threadIdx.x) >> 6;
  if (node >= n) return;
  int lane = threadIdx.x & 63;
  int beg = rowptr[node];
  int deg = rowptr[node + 1] - beg;
  float adn = adst[node];
  float2 acc = make_float2(0.f, 0.f);
  float inv;

  if (deg <= 64){
    int s = 0; float logit = -1e30f;
    if (lane < deg){
      s = csr[beg + lane];
      float xx = asrc[s] + adn;
      logit = xx >= 0.f ? xx : 0.2f * xx;
    }
    float m = wred_max(logit);
    float p = (lane < deg) ? __expf(logit - m) : 0.f;
    float denom = wred_sum(p);
    inv = 1.f / (denom + 1e-16f);
    int j = 0;
    for (; j + 4 <= deg; j += 4){
      int s0 = __shfl(s, j, 64),     s1 = __shfl(s, j + 1, 64);
      int s2 = __shfl(s, j + 2, 64), s3 = __shfl(s, j + 3, 64);
      float a0 = __shfl(p, j, 64),     a1 = __shfl(p, j + 1, 64);
      float a2 = __shfl(p, j + 2, 64), a3 = __shfl(p, j + 3, 64);
      float2 v0 = *(const float2*)&h[(size_t)s0 * D + lane * 2];
      float2 v1 = *(const float2*)&h[(size_t)s1 * D + lane * 2];
      float2 v2 = *(const float2*)&h[(size_t)s2 * D + lane * 2];
      float2 v3 = *(const float2*)&h[(size_t)s3 * D + lane * 2];
      acc.x += a0 * v0.x; acc.y += a0 * v0.y;
      acc.x += a1 * v1.x; acc.y += a1 * v1.y;
      acc.x += a2 * v2.x; acc.y += a2 * v2.y;
      acc.x += a3 * v3.x; acc.y += a3 * v3.y;
    }
    for (; j < deg; j++){
      int sj = __shfl(s, j, 64);
      float aj = __shfl(p, j, 64);
      float2 v = *(const float2*)&h[(size_t)sj * D + lane * 2];
      acc.x += aj * v.x; acc.y += aj * v.y;
    }
  } else {
    // general chunked path (deg > 64): 3 passes
    float m = -1e30f;
    for (int base = 0; base < deg; base += 64){
      float l = -1e30f;
      int idx = base + lane;
      if (idx < deg){ int sx = csr[beg + idx]; float xx = asrc[sx] + adn; l = xx >= 0.f ? xx : 0.2f * xx; }
      m = fmaxf(m, wred_max(l));
    }
    float denom = 0.f;
    for (int base = 0; base < deg; base += 64){
      float p2 = 0.f;
      int idx = base + lane;
      if (idx < deg){ int sx = csr[beg + idx]; float xx = asrc[sx] + adn; float l = xx >= 0.f ? xx : 0.2f * xx; p2 = __expf(l - m); }
      denom += wred_sum(p2);
    }
    inv = 1.f / (denom + 1e-16f);
    for (int base = 0; base < deg; base += 64){
      int cnt = deg - base; if (cnt > 64) cnt = 64;
      float p2 = 0.f; int sx = 0;
      int idx = base + lane;
      if (idx < deg){ sx = csr[beg + idx]; float xx = asrc[sx] + adn; float l = xx >= 0.f ? xx : 0.2f * xx; p2 = __expf(l - m); }
      for (int j = 0; j < cnt; j++){
        int sj = __shfl(sx, j, 64);
        float aj = __shfl(p2, j, 64);
        float2 v = *(const float2*)&h[(size_t)sj * D + lane * 2];
        acc.x += aj * v.x; acc.y += aj * v.y;
      }
    }
  }
  acc.x *= inv; acc.y *= inv;
  float2 b2 = *(const float2*)&bias[lane * 2];
  float ox = acc.x + b2.x, oy = acc.y + b2.y;
  if (relu){ ox = fmaxf(ox, 0.f); oy = fmaxf(oy, 0.f); }
  *(float2*)&out[(size_t)node * D + lane * 2] = make_float2(ox, oy);
}

// ---------------- pooling: one wave per graph (batch is sorted) ----------------
__device__ __forceinline__ int lbound(const int* a, int n, int key){
  int lo = 0, hi = n;
  while (lo < hi){ int mid = (lo + hi) >> 1; if (a[mid] < key) lo = mid + 1; else hi = mid; }
  return lo;
}

__global__ __launch_bounds__(256) void k_pool(const float* __restrict__ x,
                                              const int* __restrict__ batch,
                                              float* __restrict__ pooled, int n, int g_total){
  int g = (blockIdx.x * 256 + threadIdx.x) >> 6;
  if (g >= g_total) return;
  int lane = threadIdx.x & 63;
  int lo = lbound(batch, n, g);
  int hi = lbound(batch, n, g + 1);
  float2 acc = make_float2(0.f, 0.f);
  for (int i = lo; i < hi; i++){
    float2 v = *(const float2*)&x[(size_t)i * D + lane * 2];
    acc.x += v.x; acc.y += v.y;
  }
  float c = (float)(hi - lo);
  float invc = 1.f / fmaxf(c, 1.f);
  float2 r = make_float2(acc.x * invc, acc.y * invc);
  *(float2*)&pooled[(size_t)g * D + lane * 2] = r;
}

// ---------------- final linear: out = pooled @ lin_W + lin_b ----------------
__global__ __launch_bounds__(128) void k_final(const float* __restrict__ pooled,
                                               const float* __restrict__ Wl,
                                               const float* __restrict__ bl,
                                               float* __restrict__ out, int g_total){
  __shared__ float pl[128];
  int g = blockIdx.x;
  int c = threadIdx.x;
  pl[c] = pooled[(size_t)g * D + c];
  __syncthreads();
  float acc = bl[c];
#pragma unroll 4
  for (int k = 0; k < 128; k++) acc += pl[k] * Wl[(size_t)k * D + c];
  out[(size_t)g * D + c] = acc;
}

// ---------------- launch ----------------
extern "C" void kernel_launch(void* const* d_in, const int* in_sizes, int n_in,
                              void* d_out, int out_size, void* d_ws, size_t ws_size,
                              hipStream_t stream){
  const float* x     = (const float*)d_in[0];
  const int*   ei    = (const int*)d_in[1];
  const int*   batch = (const int*)d_in[3];
  const float* gW[3]  = {(const float*)d_in[4],  (const float*)d_in[8],  (const float*)d_in[12]};
  const float* gAs[3] = {(const float*)d_in[5],  (const float*)d_in[9],  (const float*)d_in[13]};
  const float* gAd[3] = {(const float*)d_in[6],  (const float*)d_in[10], (const float*)d_in[14]};
  const float* gB[3]  = {(const float*)d_in[7],  (const float*)d_in[11], (const float*)d_in[15]};
  const float* linW = (const float*)d_in[16];
  const float* linB = (const float*)d_in[17];
  float* outp = (float*)d_out;

  int N  = in_sizes[3];
  int E  = in_sizes[1] / 2;
  int EP = E + N;
  int G  = out_size / D;

  char* ws = (char*)d_ws;
  size_t off = 0;
  auto alloc = [&](size_t bytes)->void*{
    void* p = ws + off;
    off += (bytes + 255) & ~(size_t)255;
    return p;
  };
  float* bufP   = (float*)alloc((size_t)N * D * 4);
  float* bufQ   = (float*)alloc((size_t)N * D * 4);
  float* as_    = (float*)alloc((size_t)N * 4);
  float* ad_    = (float*)alloc((size_t)N * 4);
  int*   counts = (int*)  alloc((size_t)N * 4);
  int*   cursor = (int*)  alloc((size_t)N * 4);
  int*   rowptr = (int*)  alloc((size_t)(N + 1) * 4);
  int*   csr    = (int*)  alloc((size_t)EP * 4);
  float* pooled = (float*)alloc((size_t)G * D * 4);
  (void)ws_size; (void)n_in;

  const int* esrc = ei;
  const int* edst = ei + E;

  hipMemsetAsync(counts, 0, (size_t)N * 4, stream);
  hipMemsetAsync(cursor, 0, (size_t)N * 4, stream);

  int tpb = 256;
  int egrid = (EP + tpb - 1) / tpb;
  k_hist<<<egrid, tpb, 0, stream>>>(edst, E, EP, counts);
  k_scan<<<1, 1024, 0, stream>>>(counts, rowptr, N);
  k_fill<<<egrid, tpb, 0, stream>>>(esrc, edst, E, EP, rowptr, cursor, csr);

  int gemm_grid = (N + 63) / 64;
  int node_grid = (N + 3) / 4;
  int pool_grid = (G + 3) / 4;

  // layer 1: x -> bufP (h), agg -> bufQ, relu
  k_gemm<<<gemm_grid, tpb, 0, stream>>>(x, gW[0], bufP, N);
  k_dots<<<node_grid, tpb, 0, stream>>>(bufP, gAs[0], gAd[0], as_, ad_, N);
  k_agg <<<node_grid, tpb, 0, stream>>>(bufP, csr, rowptr, as_, ad_, gB[0], bufQ, 1, N);
  // layer 2: bufQ -> bufQ (in-place h), agg -> bufP, relu
  k_gemm<<<gemm_grid, tpb, 0, stream>>>(bufQ, gW[1], bufQ, N);
  k_dots<<<node_grid, tpb, 0, stream>>>(bufQ, gAs[1], gAd[1], as_, ad_, N);
  k_agg <<<node_grid, tpb, 0, stream>>>(bufQ, csr, rowptr, as_, ad_, gB[1], bufP, 1, N);
  // layer 3: bufP -> bufP (in-place h), agg -> bufQ, no relu
  k_gemm<<<gemm_grid, tpb, 0, stream>>>(bufP, gW[2], bufP, N);
  k_dots<<<node_grid, tpb, 0, stream>>>(bufP, gAs[2], gAd[2], as_, ad_, N);
  k_agg <<<node_grid, tpb, 0, stream>>>(bufP, csr, rowptr, as_, ad_, gB[2], bufQ, 0, N);

  // pool + final linear
  k_pool <<<pool_grid, tpb, 0, stream>>>(bufQ, batch, pooled, N, G);
  k_final<<<G, 128, 0, stream>>>(pooled, linW, linB, outp, G);
}

// Round 2
// 298.677 us; speedup vs baseline: 1.3402x; 1.3402x over previous
//
#include <hip/hip_runtime.h>

#define D 128

// ---------------- helpers ----------------
__device__ __forceinline__ float wred_max(float v){
#pragma unroll
  for (int o = 1; o < 64; o <<= 1) v = fmaxf(v, __shfl_xor(v, o, 64));
  return v;
}
__device__ __forceinline__ float wred_sum(float v){
#pragma unroll
  for (int o = 1; o < 64; o <<= 1) v += __shfl_xor(v, o, 64);
  return v;
}
__device__ __forceinline__ unsigned short f2bf(float f){
  unsigned u = __float_as_uint(f);
  unsigned r = (u + 0x7FFFu + ((u >> 16) & 1u)) >> 16;   // RNE
  return (unsigned short)r;
}

// ---------------- CSR build ----------------
__global__ __launch_bounds__(256) void k_hist(const int* __restrict__ dst, int E, int EP,
                                              int* __restrict__ counts){
  int e = blockIdx.x * blockDim.x + threadIdx.x;
  if (e >= EP) return;
  int d = (e < E) ? dst[e] : (e - E);   // tail = self loops
  atomicAdd(&counts[d], 1);
}

// hierarchical scan: per-block exclusive scan + block sums
__global__ __launch_bounds__(256) void k_scan1(const int* __restrict__ counts, int n,
                                               int* __restrict__ excl, int* __restrict__ bsum){
  __shared__ int ws[4];
  int tid = threadIdx.x, lane = tid & 63, wid = tid >> 6;
  int i = blockIdx.x * 256 + tid;
  int v = (i < n) ? counts[i] : 0;
  int x = v;
#pragma unroll
  for (int o = 1; o < 64; o <<= 1){ int t = __shfl_up(x, o, 64); if (lane >= o) x += t; }
  if (lane == 63) ws[wid] = x;
  __syncthreads();
  int s0 = ws[0], s1 = ws[1], s2 = ws[2], s3 = ws[3];
  int wo = (wid > 0 ? s0 : 0) + (wid > 1 ? s1 : 0) + (wid > 2 ? s2 : 0);
  if (i < n) excl[i] = wo + x - v;
  if (tid == 255) bsum[blockIdx.x] = wo + x;
}
__global__ __launch_bounds__(256) void k_scan2(int* __restrict__ bsum, int nb){
  __shared__ int ws[4];
  int tid = threadIdx.x, lane = tid & 63, wid = tid >> 6;
  int v = (tid < nb) ? bsum[tid] : 0;
  int x = v;
#pragma unroll
  for (int o = 1; o < 64; o <<= 1){ int t = __shfl_up(x, o, 64); if (lane >= o) x += t; }
  if (lane == 63) ws[wid] = x;
  __syncthreads();
  int s0 = ws[0], s1 = ws[1], s2 = ws[2], s3 = ws[3];
  int wo = (wid > 0 ? s0 : 0) + (wid > 1 ? s1 : 0) + (wid > 2 ? s2 : 0);
  if (tid < nb) bsum[tid] = wo + x - v;
}
__global__ __launch_bounds__(256) void k_scan3(int* __restrict__ rowptr, const int* __restrict__ bsum,
                                               int n, int total){
  int i = blockIdx.x * 256 + threadIdx.x;
  if (i < n) rowptr[i] += bsum[blockIdx.x];
  if (i == 0) rowptr[n] = total;
}

__global__ __launch_bounds__(256) void k_fill(const int* __restrict__ src, const int* __restrict__ dst,
                                              int E, int EP, const int* __restrict__ rowptr,
                                              int* __restrict__ cursor, int* __restrict__ csr){
  int e = blockIdx.x * blockDim.x + threadIdx.x;
  if (e >= EP) return;
  int s, d;
  if (e < E){ s = src[e]; d = dst[e]; } else { s = d = e - E; }
  int pos = rowptr[d] + atomicAdd(&cursor[d], 1);
  csr[pos] = s;
}

// ---------------- GEMM + fused attention dots ----------------
// C(bf16)[n x 128] = A[n x 128] @ W[128 x 128]; as_[r]=C_f32[r]·a_src; ad_[r]=C_f32[r]·a_dst
// W staged fully in LDS (64KB, one barrier). A streamed global->reg (16 lanes share a
// row -> same-address broadcast merges in L1). 8 rows x 8 cols per thread -> FMA-bound.
__global__ __launch_bounds__(256) void k_gemm_dots(const float* __restrict__ A,
                                                   const float* __restrict__ W,
                                                   const float* __restrict__ a_src,
                                                   const float* __restrict__ a_dst,
                                                   unsigned short* __restrict__ Hbf,
                                                   float* __restrict__ as_,
                                                   float* __restrict__ ad_,
                                                   int n){
  __shared__ float sW[128][128];   // 64 KB
  int tid = threadIdx.x;
  int r0 = blockIdx.x * 128;
  int tx = tid & 15;               // col groups: tx*4 and tx*4+64
  int ty = tid >> 4;               // row group: ty*8 .. ty*8+7

  // stage W (coalesced float4, 16 per thread)
#pragma unroll
  for (int i = 0; i < 16; i++){
    int slot = tid + i * 256;          // 0..4095
    int k = slot >> 5, cq = slot & 31;
    *(float4*)&sW[k][cq * 4] = *(const float4*)&W[(size_t)k * D + cq * 4];
  }
  __syncthreads();

  const float* ap[8];
#pragma unroll
  for (int i = 0; i < 8; i++){
    int gr = r0 + ty * 8 + i; if (gr > n - 1) gr = n - 1;
    ap[i] = A + (size_t)gr * D;
  }

  float4 acc0[8], acc1[8];
#pragma unroll
  for (int i = 0; i < 8; i++){ acc0[i] = make_float4(0,0,0,0); acc1[i] = make_float4(0,0,0,0); }

#pragma unroll 2
  for (int k4 = 0; k4 < 128; k4 += 4){
    float4 av[8];
#pragma unroll
    for (int i = 0; i < 8; i++) av[i] = *(const float4*)(ap[i] + k4);
#pragma unroll
    for (int kk = 0; kk < 4; kk++){
      float4 w0 = *(const float4*)&sW[k4 + kk][tx * 4];
      float4 w1 = *(const float4*)&sW[k4 + kk][tx * 4 + 64];
#pragma unroll
      for (int i = 0; i < 8; i++){
        float a = (kk == 0) ? av[i].x : (kk == 1) ? av[i].y : (kk == 2) ? av[i].z : av[i].w;
        acc0[i].x += a * w0.x; acc0[i].y += a * w0.y; acc0[i].z += a * w0.z; acc0[i].w += a * w0.w;
        acc1[i].x += a * w1.x; acc1[i].y += a * w1.y; acc1[i].z += a * w1.z; acc1[i].w += a * w1.w;
      }
    }
  }

  // fused dots: per-row partials over this thread's 8 cols, reduce across the 16 lanes
  // (tx group is contiguous within a wave: lane = (ty&3)*16 + tx)
  float4 s0 = *(const float4*)&a_src[tx * 4];
  float4 s1 = *(const float4*)&a_src[tx * 4 + 64];
  float4 d0 = *(const float4*)&a_dst[tx * 4];
  float4 d1 = *(const float4*)&a_dst[tx * 4 + 64];
  float ps[8], pd[8];
#pragma unroll
  for (int i = 0; i < 8; i++){
    ps[i] = acc0[i].x*s0.x + acc0[i].y*s0.y + acc0[i].z*s0.z + acc0[i].w*s0.w
          + acc1[i].x*s1.x + acc1[i].y*s1.y + acc1[i].z*s1.z + acc1[i].w*s1.w;
    pd[i] = acc0[i].x*d0.x + acc0[i].y*d0.y + acc0[i].z*d0.z + acc0[i].w*d0.w
          + acc1[i].x*d1.x + acc1[i].y*d1.y + acc1[i].z*d1.z + acc1[i].w*d1.w;
  }
#pragma unroll
  for (int o = 1; o < 16; o <<= 1){
#pragma unroll
    for (int i = 0; i < 8; i++){
      ps[i] += __shfl_xor(ps[i], o, 64);
      pd[i] += __shfl_xor(pd[i], o, 64);
    }
  }
#pragma unroll
  for (int i = 0; i < 8; i++){
    int r = r0 + ty * 8 + i;
    bool ok = (r < n);
    if (ok && tx == i)     as_[r] = ps[i];
    if (ok && tx == 8 + i) ad_[r] = pd[i];
  }

  // store h as bf16
#pragma unroll
  for (int i = 0; i < 8; i++){
    int r = r0 + ty * 8 + i;
    if (r < n){
      ushort4 u0, u1;
      u0.x = f2bf(acc0[i].x); u0.y = f2bf(acc0[i].y); u0.z = f2bf(acc0[i].z); u0.w = f2bf(acc0[i].w);
      u1.x = f2bf(acc1[i].x); u1.y = f2bf(acc1[i].y); u1.z = f2bf(acc1[i].z); u1.w = f2bf(acc1[i].w);
      *(ushort4*)&Hbf[(size_t)r * D + tx * 4]      = u0;
      *(ushort4*)&Hbf[(size_t)r * D + tx * 4 + 64] = u1;
    }
  }
}

// ---------------- aggregation: one wave per destination node, bf16 gather ----------------
__global__ __launch_bounds__(256) void k_agg(const unsigned int* __restrict__ hb,  // bf16x2 rows
                                             const int* __restrict__ csr,
                                             const int* __restrict__ rowptr,
                                             const float* __restrict__ asrc,
                                             const float* __restrict__ adst,
                                             const float* __restrict__ bias,
                                             float* __restrict__ out, int relu, int n){
  int node = (blockIdx.x * 256 + threadIdx.x) >> 6;
  if (node >= n) return;
  int lane = threadIdx.x & 63;
  int beg = rowptr[node];
  int deg = rowptr[node + 1] - beg;
  float adn = adst[node];
  float2 acc = make_float2(0.f, 0.f);
  float inv;

  if (deg <= 64){
    int s = 0; float logit = -1e30f;
    if (lane < deg){
      s = csr[beg + lane];
      float xx = asrc[s] + adn;
      logit = xx >= 0.f ? xx : 0.2f * xx;
    }
    float m = wred_max(logit);
    float p = (lane < deg) ? __expf(logit - m) : 0.f;
    float denom = wred_sum(p);
    inv = 1.f / (denom + 1e-16f);
    int j = 0;
    for (; j + 4 <= deg; j += 4){
      int s0 = __shfl(s, j, 64),     s1 = __shfl(s, j + 1, 64);
      int s2 = __shfl(s, j + 2, 64), s3 = __shfl(s, j + 3, 64);
      float a0 = __shfl(p, j, 64),     a1 = __shfl(p, j + 1, 64);
      float a2 = __shfl(p, j + 2, 64), a3 = __shfl(p, j + 3, 64);
      unsigned v0 = hb[((size_t)s0 << 6) + lane];
      unsigned v1 = hb[((size_t)s1 << 6) + lane];
      unsigned v2 = hb[((size_t)s2 << 6) + lane];
      unsigned v3 = hb[((size_t)s3 << 6) + lane];
      acc.x += a0 * __uint_as_float(v0 << 16); acc.y += a0 * __uint_as_float(v0 & 0xFFFF0000u);
      acc.x += a1 * __uint_as_float(v1 << 16); acc.y += a1 * __uint_as_float(v1 & 0xFFFF0000u);
      acc.x += a2 * __uint_as_float(v2 << 16); acc.y += a2 * __uint_as_float(v2 & 0xFFFF0000u);
      acc.x += a3 * __uint_as_float(v3 << 16); acc.y += a3 * __uint_as_float(v3 & 0xFFFF0000u);
    }
    for (; j < deg; j++){
      int sj = __shfl(s, j, 64);
      float aj = __shfl(p, j, 64);
      unsigned v = hb[((size_t)sj << 6) + lane];
      acc.x += aj * __uint_as_float(v << 16); acc.y += aj * __uint_as_float(v & 0xFFFF0000u);
    }
  } else {
    // general chunked path (deg > 64): 3 passes
    float m = -1e30f;
    for (int base = 0; base < deg; base += 64){
      float l = -1e30f;
      int idx = base + lane;
      if (idx < deg){ int sx = csr[beg + idx]; float xx = asrc[sx] + adn; l = xx >= 0.f ? xx : 0.2f * xx; }
      m = fmaxf(m, wred_max(l));
    }
    float denom = 0.f;
    for (int base = 0; base < deg; base += 64){
      float p2 = 0.f;
      int idx = base + lane;
      if (idx < deg){ int sx = csr[beg + idx]; float xx = asrc[sx] + adn; float l = xx >= 0.f ? xx : 0.2f * xx; p2 = __expf(l - m); }
      denom += wred_sum(p2);
    }
    inv = 1.f / (denom + 1e-16f);
    for (int base = 0; base < deg; base += 64){
      int cnt = deg - base; if (cnt > 64) cnt = 64;
      float p2 = 0.f; int sx = 0;
      int idx = base + lane;
      if (idx < deg){ sx = csr[beg + idx]; float xx = asrc[sx] + adn; float l = xx >= 0.f ? xx : 0.2f * xx; p2 = __expf(l - m); }
      for (int j = 0; j < cnt; j++){
        int sj = __shfl(sx, j, 64);
        float aj = __shfl(p2, j, 64);
        unsigned v = hb[((size_t)sj << 6) + lane];
        acc.x += aj * __uint_as_float(v << 16); acc.y += aj * __uint_as_float(v & 0xFFFF0000u);
      }
    }
  }
  acc.x *= inv; acc.y *= inv;
  float2 b2 = *(const float2*)&bias[lane * 2];
  float ox = acc.x + b2.x, oy = acc.y + b2.y;
  if (relu){ ox = fmaxf(ox, 0.f); oy = fmaxf(oy, 0.f); }
  *(float2*)&out[(size_t)node * D + lane * 2] = make_float2(ox, oy);
}

// ---------------- pooling: one wave per graph (batch is sorted) ----------------
__device__ __forceinline__ int lbound(const int* a, int n, int key){
  int lo = 0, hi = n;
  while (lo < hi){ int mid = (lo + hi) >> 1; if (a[mid] < key) lo = mid + 1; else hi = mid; }
  return lo;
}

__global__ __launch_bounds__(256) void k_pool(const float* __restrict__ x,
                                              const int* __restrict__ batch,
                                              float* __restrict__ pooled, int n, int g_total){
  int g = (blockIdx.x * 256 + threadIdx.x) >> 6;
  if (g >= g_total) return;
  int lane = threadIdx.x & 63;
  int lo = lbound(batch, n, g);
  int hi = lbound(batch, n, g + 1);
  float2 acc = make_float2(0.f, 0.f);
  for (int i = lo; i < hi; i++){
    float2 v = *(const float2*)&x[(size_t)i * D + lane * 2];
    acc.x += v.x; acc.y += v.y;
  }
  float c = (float)(hi - lo);
  float invc = 1.f / fmaxf(c, 1.f);
  *(float2*)&pooled[(size_t)g * D + lane * 2] = make_float2(acc.x * invc, acc.y * invc);
}

// ---------------- final linear ----------------
__global__ __launch_bounds__(128) void k_final(const float* __restrict__ pooled,
                                               const float* __restrict__ Wl,
                                               const float* __restrict__ bl,
                                               float* __restrict__ out, int g_total){
  __shared__ float pl[128];
  int g = blockIdx.x;
  int c = threadIdx.x;
  pl[c] = pooled[(size_t)g * D + c];
  __syncthreads();
  float acc = bl[c];
#pragma unroll 4
  for (int k = 0; k < 128; k++) acc += pl[k] * Wl[(size_t)k * D + c];
  out[(size_t)g * D + c] = acc;
}

// ---------------- launch ----------------
extern "C" void kernel_launch(void* const* d_in, const int* in_sizes, int n_in,
                              void* d_out, int out_size, void* d_ws, size_t ws_size,
                              hipStream_t stream){
  const float* x     = (const float*)d_in[0];
  const int*   ei    = (const int*)d_in[1];
  const int*   batch = (const int*)d_in[3];
  const float* gW[3]  = {(const float*)d_in[4],  (const float*)d_in[8],  (const float*)d_in[12]};
  const float* gAs[3] = {(const float*)d_in[5],  (const float*)d_in[9],  (const float*)d_in[13]};
  const float* gAd[3] = {(const float*)d_in[6],  (const float*)d_in[10], (const float*)d_in[14]};
  const float* gB[3]  = {(const float*)d_in[7],  (const float*)d_in[11], (const float*)d_in[15]};
  const float* linW = (const float*)d_in[16];
  const float* linB = (const float*)d_in[17];
  float* outp = (float*)d_out;

  int N  = in_sizes[3];
  int E  = in_sizes[1] / 2;
  int EP = E + N;
  int G  = out_size / D;

  char* ws = (char*)d_ws;
  size_t off = 0;
  auto alloc = [&](size_t bytes)->void*{
    void* p = ws + off;
    off += (bytes + 255) & ~(size_t)255;
    return p;
  };
  float*          bufA   = (float*)alloc((size_t)N * D * 4);
  unsigned short* Hbf    = (unsigned short*)alloc((size_t)N * D * 2);
  float*          as_    = (float*)alloc((size_t)N * 4);
  float*          ad_    = (float*)alloc((size_t)N * 4);
  int*            counts = (int*)  alloc((size_t)N * 4);
  int*            cursor = (int*)  alloc((size_t)N * 4);
  int*            rowptr = (int*)  alloc((size_t)(N + 1) * 4);
  int*            csr    = (int*)  alloc((size_t)EP * 4);
  int*            bsum   = (int*)  alloc(1024 * 4);
  float*          pooled = (float*)alloc((size_t)G * D * 4);
  (void)ws_size; (void)n_in;

  const int* esrc = ei;
  const int* edst = ei + E;

  hipMemsetAsync(counts, 0, (size_t)N * 4, stream);
  hipMemsetAsync(cursor, 0, (size_t)N * 4, stream);

  int tpb = 256;
  int egrid = (EP + tpb - 1) / tpb;
  int ngrid = (N + tpb - 1) / tpb;    // also = scan block count

  k_hist <<<egrid, tpb, 0, stream>>>(edst, E, EP, counts);
  k_scan1<<<ngrid, tpb, 0, stream>>>(counts, N, rowptr, bsum);
  k_scan2<<<1,     tpb, 0, stream>>>(bsum, ngrid);
  k_scan3<<<ngrid, tpb, 0, stream>>>(rowptr, bsum, N, EP);
  k_fill <<<egrid, tpb, 0, stream>>>(esrc, edst, E, EP, rowptr, cursor, csr);

  int gemm_grid = (N + 127) / 128;
  int node_grid = (N + 3) / 4;
  int pool_grid = (G + 3) / 4;
  const unsigned int* hbu = (const unsigned int*)Hbf;

  // layer 1
  k_gemm_dots<<<gemm_grid, tpb, 0, stream>>>(x, gW[0], gAs[0], gAd[0], Hbf, as_, ad_, N);
  k_agg      <<<node_grid, tpb, 0, stream>>>(hbu, csr, rowptr, as_, ad_, gB[0], bufA, 1, N);
  // layer 2
  k_gemm_dots<<<gemm_grid, tpb, 0, stream>>>(bufA, gW[1], gAs[1], gAd[1], Hbf, as_, ad_, N);
  k_agg      <<<node_grid, tpb, 0, stream>>>(hbu, csr, rowptr, as_, ad_, gB[1], bufA, 1, N);
  // layer 3
  k_gemm_dots<<<gemm_grid, tpb, 0, stream>>>(bufA, gW[2], gAs[2], gAd[2], Hbf, as_, ad_, N);
  k_agg      <<<node_grid, tpb, 0, stream>>>(hbu, csr, rowptr, as_, ad_, gB[2], bufA, 0, N);

  // pool + final linear
  k_pool <<<pool_grid, tpb, 0, stream>>>(bufA, batch, pooled, N, G);
  k_final<<<G, 128, 0, stream>>>(pooled, linW, linB, outp, G);
}